// Round 1
// baseline (538.592 us; speedup 1.0000x reference)
//
#include <hip/hip_runtime.h>
#include <stdint.h>

#define TPB 256
#define NB1 2048   // bits [31:21]
#define NB2 2048   // bits [20:10]
#define NB3 1024   // bits [9:0]
#define CAP 4096   // LDS candidate buffer (expected ~1100 for this data)
#define DCOLS 65536

// Monotone transform: larger float -> larger unsigned key
__device__ __forceinline__ unsigned f2key(float f) {
  unsigned u = __float_as_uint(f);
  unsigned m = ((int)u >> 31) | 0x80000000u;
  return u ^ m;
}
__device__ __forceinline__ float key2f(unsigned k) {
  unsigned u = (k & 0x80000000u) ? (k ^ 0x80000000u) : ~k;
  return __uint_as_float(u);
}

// Find, scanning bins from HIGH to LOW, the bin where the cumulative count
// (from the top) reaches K. Writes bin -> *selbin, rank-within-bin -> *selrem.
// All threads must call; ends with a barrier.
__device__ void find_top(const unsigned* hist, int NB, unsigned K,
                         unsigned* scan, unsigned* selbin, unsigned* selrem) {
  const int tid = threadIdx.x;
  const int C = NB / TPB;
  unsigned cs = 0;
  for (int i = 0; i < C; ++i) cs += hist[tid * C + i];
  scan[tid] = cs;
  __syncthreads();
  // Hillis-Steele inclusive suffix scan: suff[t] = sum of chunks t..TPB-1
  unsigned suff = cs;
  for (int off = 1; off < TPB; off <<= 1) {
    unsigned add = (tid + off < TPB) ? scan[tid + off] : 0u;
    __syncthreads();
    suff += add;
    scan[tid] = suff;
    __syncthreads();
  }
  unsigned above = suff - cs;   // count in all chunks strictly above mine
  if (above < K && suff >= K) { // exactly one thread wins
    unsigned cAbove = above;
    for (int bin = tid * C + C - 1; bin >= tid * C; --bin) {
      unsigned c = hist[bin];
      if (cAbove + c >= K) { *selbin = (unsigned)bin; *selrem = K - cAbove; break; }
      cAbove += c;
    }
  }
  __syncthreads();
}

__global__ void __launch_bounds__(TPB)
topk_select(const float* __restrict__ in, const int* __restrict__ kptr,
            unsigned* __restrict__ rowkey) {
  __shared__ unsigned h1[NB1];
  __shared__ unsigned h2[NB2];
  __shared__ unsigned h3[NB3];
  __shared__ unsigned cand[CAP];
  __shared__ unsigned scan[TPB];
  __shared__ unsigned sel_bin, sel_rem, cand_cnt;

  const int tid = threadIdx.x;
  const int row = blockIdx.x;
  const unsigned K = (unsigned)(*kptr);

  for (int i = tid; i < NB1; i += TPB) h1[i] = 0u;
  for (int i = tid; i < NB2; i += TPB) h2[i] = 0u;
  for (int i = tid; i < NB3; i += TPB) h3[i] = 0u;
  if (tid == 0) cand_cnt = 0u;
  __syncthreads();

  const float4* rowv = (const float4*)(in + (size_t)row * DCOLS);
  const int n4 = DCOLS / 4;

  // ---- Pass 1: histogram of top 11 bits ----
  for (int i = tid; i < n4; i += TPB) {
    float4 v = rowv[i];
    atomicAdd(&h1[f2key(v.x) >> 21], 1u);
    atomicAdd(&h1[f2key(v.y) >> 21], 1u);
    atomicAdd(&h1[f2key(v.z) >> 21], 1u);
    atomicAdd(&h1[f2key(v.w) >> 21], 1u);
  }
  __syncthreads();
  find_top(h1, NB1, K, scan, &sel_bin, &sel_rem);
  const unsigned b1 = sel_bin;
  const unsigned K2 = sel_rem;
  __syncthreads();

  // ---- Pass 2: re-read row, histogram next 11 bits of matching keys,
  //      and compact matching keys into LDS ----
  for (int i = tid; i < n4; i += TPB) {
    float4 v = rowv[i];
    unsigned kk;
    kk = f2key(v.x);
    if ((kk >> 21) == b1) { atomicAdd(&h2[(kk >> 10) & (NB2 - 1)], 1u);
      unsigned p = atomicAdd(&cand_cnt, 1u); if (p < CAP) cand[p] = kk; }
    kk = f2key(v.y);
    if ((kk >> 21) == b1) { atomicAdd(&h2[(kk >> 10) & (NB2 - 1)], 1u);
      unsigned p = atomicAdd(&cand_cnt, 1u); if (p < CAP) cand[p] = kk; }
    kk = f2key(v.z);
    if ((kk >> 21) == b1) { atomicAdd(&h2[(kk >> 10) & (NB2 - 1)], 1u);
      unsigned p = atomicAdd(&cand_cnt, 1u); if (p < CAP) cand[p] = kk; }
    kk = f2key(v.w);
    if ((kk >> 21) == b1) { atomicAdd(&h2[(kk >> 10) & (NB2 - 1)], 1u);
      unsigned p = atomicAdd(&cand_cnt, 1u); if (p < CAP) cand[p] = kk; }
  }
  __syncthreads();
  find_top(h2, NB2, K2, scan, &sel_bin, &sel_rem);
  const unsigned b2 = sel_bin;
  const unsigned K3 = sel_rem;
  const unsigned nc = cand_cnt;
  __syncthreads();

  // ---- Pass 3: histogram low 10 bits from LDS candidates (or global fallback) ----
  if (nc <= CAP) {
    for (unsigned i = tid; i < nc; i += TPB) {
      unsigned kk = cand[i];
      if (((kk >> 10) & (NB2 - 1)) == b2) atomicAdd(&h3[kk & (NB3 - 1)], 1u);
    }
  } else {
    const unsigned pfx = (b1 << 11) | b2;
    for (int i = tid; i < n4; i += TPB) {
      float4 v = rowv[i];
      unsigned kk;
      kk = f2key(v.x); if ((kk >> 10) == pfx) atomicAdd(&h3[kk & (NB3 - 1)], 1u);
      kk = f2key(v.y); if ((kk >> 10) == pfx) atomicAdd(&h3[kk & (NB3 - 1)], 1u);
      kk = f2key(v.z); if ((kk >> 10) == pfx) atomicAdd(&h3[kk & (NB3 - 1)], 1u);
      kk = f2key(v.w); if ((kk >> 10) == pfx) atomicAdd(&h3[kk & (NB3 - 1)], 1u);
    }
  }
  __syncthreads();
  find_top(h3, NB3, K3, scan, &sel_bin, &sel_rem);
  if (tid == 0) rowkey[row] = (b1 << 21) | (b2 << 10) | sel_bin;
}

__global__ void __launch_bounds__(TPB)
minreduce(const unsigned* __restrict__ rowkey, unsigned* __restrict__ thr, int n) {
  __shared__ unsigned s[TPB];
  unsigned m = 0xFFFFFFFFu;
  for (int i = threadIdx.x; i < n; i += TPB) m = min(m, rowkey[i]);
  s[threadIdx.x] = m;
  __syncthreads();
  for (int off = TPB / 2; off > 0; off >>= 1) {
    if (threadIdx.x < off) s[threadIdx.x] = min(s[threadIdx.x], s[threadIdx.x + off]);
    __syncthreads();
  }
  if (threadIdx.x == 0) thr[0] = s[0];
}

__global__ void __launch_bounds__(TPB)
maskk(const float4* __restrict__ in, float4* __restrict__ out,
      const unsigned* __restrict__ thrkey, int n4) {
  const float thr = key2f(thrkey[0]);
  int idx = blockIdx.x * TPB + threadIdx.x;
  int stride = gridDim.x * TPB;
  for (int i = idx; i < n4; i += stride) {
    float4 v = in[i];
    float4 o;
    o.x = (v.x >= thr) ? v.x : 0.0f;
    o.y = (v.y >= thr) ? v.y : 0.0f;
    o.z = (v.z >= thr) ? v.z : 0.0f;
    o.w = (v.w >= thr) ? v.w : 0.0f;
    out[i] = o;
  }
}

extern "C" void kernel_launch(void* const* d_in, const int* in_sizes, int n_in,
                              void* d_out, int out_size, void* d_ws, size_t ws_size,
                              hipStream_t stream) {
  const float* in = (const float*)d_in[0];
  const int* kptr = (const int*)d_in[1];
  float* out = (float*)d_out;
  unsigned* rowkey = (unsigned*)d_ws;
  unsigned* thr = rowkey + 1024;

  const int B = in_sizes[0] / DCOLS;          // 1024 rows
  const int n4 = out_size / 4;                // 16M float4

  hipLaunchKernelGGL(topk_select, dim3(B), dim3(TPB), 0, stream, in, kptr, rowkey);
  hipLaunchKernelGGL(minreduce, dim3(1), dim3(TPB), 0, stream, rowkey, thr, B);
  hipLaunchKernelGGL(maskk, dim3(2048), dim3(TPB), 0, stream,
                     (const float4*)in, (float4*)out, thr, n4);
}

// Round 3
// 512.345 us; speedup vs baseline: 1.0512x; 1.0512x over previous
//
#include <hip/hip_runtime.h>
#include <stdint.h>

#define TPB 256
#define NBH 2048    // histogram bins for bits [31:21] and [20:10]
#define NB3 1024    // bins for bits [9:0]
#define CAP 6144    // LDS candidate buffer (expected ~2600 for gaussian data)
#define DCOLS 65536
#define NSAMP 4096

// Monotone transform: larger float -> larger unsigned key
__device__ __forceinline__ unsigned f2key(float f) {
  unsigned u = __float_as_uint(f);
  unsigned m = ((int)u >> 31) | 0x80000000u;
  return u ^ m;
}
__device__ __forceinline__ float key2f(unsigned k) {
  unsigned u = (k & 0x80000000u) ? (k ^ 0x80000000u) : ~k;
  return __uint_as_float(u);
}

__device__ __forceinline__ void clear_hist(unsigned* hist, int NB) {
  for (int i = threadIdx.x; i < NB; i += TPB) hist[i] = 0u;
}

// Find, scanning bins HIGH->LOW, the bin where cumulative count (from top)
// reaches K. All threads call; ends with a barrier.
__device__ void find_top(const unsigned* hist, int NB, unsigned K,
                         unsigned* scan, unsigned* selbin, unsigned* selrem) {
  const int tid = threadIdx.x;
  const int C = NB / TPB;
  unsigned cs = 0;
  for (int i = 0; i < C; ++i) cs += hist[tid * C + i];
  scan[tid] = cs;
  __syncthreads();
  unsigned suff = cs;
  for (int off = 1; off < TPB; off <<= 1) {
    unsigned add = (tid + off < TPB) ? scan[tid + off] : 0u;
    __syncthreads();
    suff += add;
    scan[tid] = suff;
    __syncthreads();
  }
  unsigned above = suff - cs;
  if (above < K && suff >= K) {
    unsigned cAbove = above;
    for (int bin = tid * C + C - 1; bin >= tid * C; --bin) {
      unsigned c = hist[bin];
      if (cAbove + c >= K) { *selbin = (unsigned)bin; *selrem = K - cAbove; break; }
      cAbove += c;
    }
  }
  __syncthreads();
}

__global__ void __launch_bounds__(TPB)
topk_select(const float* __restrict__ in, const int* __restrict__ kptr,
            unsigned* __restrict__ rowkey) {
  __shared__ unsigned hist[NBH];
  __shared__ unsigned scan[TPB];
  __shared__ unsigned cand[CAP];
  __shared__ unsigned sel_bin, sel_rem, cand_cnt;

  const int tid = threadIdx.x;
  const int lane = tid & 63;
  const int row = blockIdx.x;
  const unsigned K = (unsigned)(*kptr);
  const float4* rowv = (const float4*)(in + (size_t)row * DCOLS);
  const int n4 = DCOLS / 4;

  // ---- Phase S: histogram a 4096-elem sample, pick pivot bin ----
  clear_hist(hist, NBH);
  if (tid == 0) cand_cnt = 0u;
  __syncthreads();
  for (int j = 0; j < NSAMP / 4 / TPB; ++j) {
    float4 v = rowv[tid + j * TPB];
    atomicAdd(&hist[f2key(v.x) >> 21], 1u);
    atomicAdd(&hist[f2key(v.y) >> 21], 1u);
    atomicAdd(&hist[f2key(v.z) >> 21], 1u);
    atomicAdd(&hist[f2key(v.w) >> 21], 1u);
  }
  __syncthreads();
  unsigned ksamp = K >> 3;                 // 2x oversample vs K*NSAMP/DCOLS
  if (ksamp < 32u) ksamp = 32u;
  if (ksamp > NSAMP - 1) ksamp = NSAMP - 1;
  find_top(hist, NBH, ksamp, scan, &sel_bin, &sel_rem);
  const unsigned tlo = sel_bin << 21;      // pivot: bin floor <= ksamp-th sample
  __syncthreads();

  // ---- Phase C: full-row read, wave-aggregated compaction of keys >= tlo ----
  for (int i = tid; i < n4; i += TPB) {
    float4 v = rowv[i];
    unsigned kx = f2key(v.x), ky = f2key(v.y), kz = f2key(v.z), kw = f2key(v.w);
#define CPCT(kk)                                                               \
    {                                                                          \
      bool p = (kk) >= tlo;                                                    \
      unsigned long long m = __ballot(p);                                      \
      if (m) {                                                                 \
        unsigned base = 0;                                                     \
        if (lane == 0) base = atomicAdd(&cand_cnt, (unsigned)__popcll(m));     \
        base = __shfl(base, 0);                                                \
        if (p) {                                                               \
          unsigned off = base + (unsigned)__popcll(m & ((1ull << lane) - 1ull));\
          if (off < CAP) cand[off] = (kk);                                     \
        }                                                                      \
      }                                                                        \
    }
    CPCT(kx) CPCT(ky) CPCT(kz) CPCT(kw)
#undef CPCT
  }
  __syncthreads();
  const unsigned nc = cand_cnt;
  __syncthreads();

  if (nc >= K && nc <= CAP) {
    // ---- Phase R: exact 3-level radix select over LDS candidates ----
    clear_hist(hist, NBH); __syncthreads();
    for (unsigned i = tid; i < nc; i += TPB) atomicAdd(&hist[cand[i] >> 21], 1u);
    __syncthreads();
    find_top(hist, NBH, K, scan, &sel_bin, &sel_rem);
    const unsigned b1 = sel_bin, K2 = sel_rem;
    __syncthreads();

    clear_hist(hist, NBH); __syncthreads();
    for (unsigned i = tid; i < nc; i += TPB) {
      unsigned kk = cand[i];
      if ((kk >> 21) == b1) atomicAdd(&hist[(kk >> 10) & (NBH - 1)], 1u);
    }
    __syncthreads();
    find_top(hist, NBH, K2, scan, &sel_bin, &sel_rem);
    const unsigned b2 = sel_bin, K3 = sel_rem;
    __syncthreads();

    clear_hist(hist, NB3); __syncthreads();
    const unsigned pfx = (b1 << 11) | b2;
    for (unsigned i = tid; i < nc; i += TPB) {
      unsigned kk = cand[i];
      if ((kk >> 10) == pfx) atomicAdd(&hist[kk & (NB3 - 1)], 1u);
    }
    __syncthreads();
    find_top(hist, NB3, K3, scan, &sel_bin, &sel_rem);
    if (tid == 0) rowkey[row] = (b1 << 21) | (b2 << 10) | sel_bin;
  } else {
    // ---- Fallback: exact 3-pass global radix select (any data) ----
    clear_hist(hist, NBH); __syncthreads();
    for (int i = tid; i < n4; i += TPB) {
      float4 v = rowv[i];
      atomicAdd(&hist[f2key(v.x) >> 21], 1u);
      atomicAdd(&hist[f2key(v.y) >> 21], 1u);
      atomicAdd(&hist[f2key(v.z) >> 21], 1u);
      atomicAdd(&hist[f2key(v.w) >> 21], 1u);
    }
    __syncthreads();
    find_top(hist, NBH, K, scan, &sel_bin, &sel_rem);
    const unsigned b1 = sel_bin, K2 = sel_rem;
    __syncthreads();

    clear_hist(hist, NBH); __syncthreads();
    for (int i = tid; i < n4; i += TPB) {
      float4 v = rowv[i];
      unsigned kk;
      kk = f2key(v.x); if ((kk >> 21) == b1) atomicAdd(&hist[(kk >> 10) & (NBH - 1)], 1u);
      kk = f2key(v.y); if ((kk >> 21) == b1) atomicAdd(&hist[(kk >> 10) & (NBH - 1)], 1u);
      kk = f2key(v.z); if ((kk >> 21) == b1) atomicAdd(&hist[(kk >> 10) & (NBH - 1)], 1u);
      kk = f2key(v.w); if ((kk >> 21) == b1) atomicAdd(&hist[(kk >> 10) & (NBH - 1)], 1u);
    }
    __syncthreads();
    find_top(hist, NBH, K2, scan, &sel_bin, &sel_rem);
    const unsigned b2 = sel_bin, K3 = sel_rem;
    __syncthreads();

    clear_hist(hist, NB3); __syncthreads();
    const unsigned pfx = (b1 << 11) | b2;
    for (int i = tid; i < n4; i += TPB) {
      float4 v = rowv[i];
      unsigned kk;
      kk = f2key(v.x); if ((kk >> 10) == pfx) atomicAdd(&hist[kk & (NB3 - 1)], 1u);
      kk = f2key(v.y); if ((kk >> 10) == pfx) atomicAdd(&hist[kk & (NB3 - 1)], 1u);
      kk = f2key(v.z); if ((kk >> 10) == pfx) atomicAdd(&hist[kk & (NB3 - 1)], 1u);
      kk = f2key(v.w); if ((kk >> 10) == pfx) atomicAdd(&hist[kk & (NB3 - 1)], 1u);
    }
    __syncthreads();
    find_top(hist, NB3, K3, scan, &sel_bin, &sel_rem);
    if (tid == 0) rowkey[row] = (b1 << 21) | (b2 << 10) | sel_bin;
  }
}

__global__ void __launch_bounds__(TPB)
minreduce(const unsigned* __restrict__ rowkey, unsigned* __restrict__ thr, int n) {
  __shared__ unsigned s[TPB];
  unsigned m = 0xFFFFFFFFu;
  for (int i = threadIdx.x; i < n; i += TPB) m = min(m, rowkey[i]);
  s[threadIdx.x] = m;
  __syncthreads();
  for (int off = TPB / 2; off > 0; off >>= 1) {
    if (threadIdx.x < off) s[threadIdx.x] = min(s[threadIdx.x], s[threadIdx.x + off]);
    __syncthreads();
  }
  if (threadIdx.x == 0) thr[0] = s[0];
}

__global__ void __launch_bounds__(TPB)
maskk(const float4* __restrict__ in, float4* __restrict__ out,
      const unsigned* __restrict__ thrkey, int n4) {
  const float thr = key2f(thrkey[0]);
  int idx = blockIdx.x * TPB + threadIdx.x;
  int stride = gridDim.x * TPB;
  for (int i = idx; i < n4; i += stride) {
    float4 v = in[i];
    float4 o;
    o.x = (v.x >= thr) ? v.x : 0.0f;
    o.y = (v.y >= thr) ? v.y : 0.0f;
    o.z = (v.z >= thr) ? v.z : 0.0f;
    o.w = (v.w >= thr) ? v.w : 0.0f;
    out[i] = o;
  }
}

extern "C" void kernel_launch(void* const* d_in, const int* in_sizes, int n_in,
                              void* d_out, int out_size, void* d_ws, size_t ws_size,
                              hipStream_t stream) {
  const float* in = (const float*)d_in[0];
  const int* kptr = (const int*)d_in[1];
  float* out = (float*)d_out;
  unsigned* rowkey = (unsigned*)d_ws;
  unsigned* thr = rowkey + 1024;

  const int B = in_sizes[0] / DCOLS;   // 1024 rows
  const int n4 = out_size / 4;         // 16M float4

  hipLaunchKernelGGL(topk_select, dim3(B), dim3(TPB), 0, stream, in, kptr, rowkey);
  hipLaunchKernelGGL(minreduce, dim3(1), dim3(TPB), 0, stream, rowkey, thr, B);
  hipLaunchKernelGGL(maskk, dim3(4096), dim3(TPB), 0, stream,
                     (const float4*)in, (float4*)out, thr, n4);
}

// Round 5
// 486.459 us; speedup vs baseline: 1.1072x; 1.0532x over previous
//
#include <hip/hip_runtime.h>
#include <stdint.h>

#define TPB 256
#define NBH 2048    // histogram bins for bits [31:21] and [20:10]
#define NB3 1024    // bins for bits [9:0]
#define CAP 6144    // LDS candidate buffer (expected ~2600 for gaussian data)
#define DCOLS 65536
#define NSAMP 4096

typedef float f4 __attribute__((ext_vector_type(4)));

// Monotone transform: larger float -> larger unsigned key
__device__ __forceinline__ unsigned f2key(float f) {
  unsigned u = __float_as_uint(f);
  unsigned m = ((int)u >> 31) | 0x80000000u;
  return u ^ m;
}
__device__ __forceinline__ float key2f(unsigned k) {
  unsigned u = (k & 0x80000000u) ? (k ^ 0x80000000u) : ~k;
  return __uint_as_float(u);
}

__device__ __forceinline__ void clear_hist(unsigned* hist, int NB) {
  for (int i = threadIdx.x; i < NB; i += TPB) hist[i] = 0u;
}

// Find, scanning bins HIGH->LOW, the bin where cumulative count (from top)
// reaches K. All threads call; ends with a barrier.
// Scan cost: 3 barriers (single-wave shfl suffix-scan, not Hillis-Steele).
__device__ void find_top(const unsigned* hist, int NB, unsigned K,
                         unsigned* scan, unsigned* selbin, unsigned* selrem) {
  const int tid = threadIdx.x;
  const int C = NB / TPB;
  unsigned cs = 0;
  for (int i = 0; i < C; ++i) cs += hist[tid * C + i];
  scan[tid] = cs;
  __syncthreads();
  if (tid < 64) {
    // lane owns 4 consecutive chunk entries
    unsigned e0 = scan[tid * 4 + 0], e1 = scan[tid * 4 + 1];
    unsigned e2 = scan[tid * 4 + 2], e3 = scan[tid * 4 + 3];
    unsigned s = e0 + e1 + e2 + e3;
    unsigned suff = s;                       // wave suffix-scan (inclusive)
    for (int off = 1; off < 64; off <<= 1) {
      unsigned t = __shfl_down(suff, off);
      if (tid + off < 64) suff += t;
    }
    unsigned tail = suff - s;                // sum of chunks after my 4
    scan[tid * 4 + 3] = e3 + tail;
    scan[tid * 4 + 2] = e2 + e3 + tail;
    scan[tid * 4 + 1] = e1 + e2 + e3 + tail;
    scan[tid * 4 + 0] = s + tail;
  }
  __syncthreads();
  unsigned suff = scan[tid];                 // sum of chunks tid..TPB-1
  unsigned above = suff - cs;
  if (above < K && suff >= K) {              // exactly one thread wins
    unsigned cAbove = above;
    for (int bin = tid * C + C - 1; bin >= tid * C; --bin) {
      unsigned c = hist[bin];
      if (cAbove + c >= K) { *selbin = (unsigned)bin; *selrem = K - cAbove; break; }
      cAbove += c;
    }
  }
  __syncthreads();
}

__global__ void __launch_bounds__(TPB)
topk_select(const float* __restrict__ in, const int* __restrict__ kptr,
            unsigned* __restrict__ rowkey) {
  __shared__ unsigned hist[NBH];
  __shared__ unsigned scan[TPB];
  __shared__ unsigned cand[CAP];
  __shared__ unsigned sel_bin, sel_rem, cand_cnt;

  const int tid = threadIdx.x;
  const int lane = tid & 63;
  const int row = blockIdx.x;
  const unsigned K = (unsigned)(*kptr);
  const f4* rowv = (const f4*)(in + (size_t)row * DCOLS);
  const int n4 = DCOLS / 4;

  // ---- Phase S: histogram a 4096-elem sample, pick pivot bin ----
  clear_hist(hist, NBH);
  if (tid == 0) cand_cnt = 0u;
  __syncthreads();
  for (int j = 0; j < NSAMP / 4 / TPB; ++j) {
    f4 v = rowv[tid + j * TPB];
    atomicAdd(&hist[f2key(v.x) >> 21], 1u);
    atomicAdd(&hist[f2key(v.y) >> 21], 1u);
    atomicAdd(&hist[f2key(v.z) >> 21], 1u);
    atomicAdd(&hist[f2key(v.w) >> 21], 1u);
  }
  __syncthreads();
  unsigned ksamp = K >> 3;                 // 2x oversample vs K*NSAMP/DCOLS
  if (ksamp < 32u) ksamp = 32u;
  if (ksamp > NSAMP - 1) ksamp = NSAMP - 1;
  find_top(hist, NBH, ksamp, scan, &sel_bin, &sel_rem);
  const unsigned tlo = sel_bin << 21;      // pivot: bin floor <= ksamp-th sample
  __syncthreads();

  // ---- Phase C: full-row read, wave-aggregated compaction of keys >= tlo ----
  for (int i = tid; i < n4; i += TPB) {
    f4 v = rowv[i];
    unsigned kx = f2key(v.x), ky = f2key(v.y), kz = f2key(v.z), kw = f2key(v.w);
#define CPCT(kk)                                                               \
    {                                                                          \
      bool p = (kk) >= tlo;                                                    \
      unsigned long long m = __ballot(p);                                      \
      if (m) {                                                                 \
        unsigned base = 0;                                                     \
        if (lane == 0) base = atomicAdd(&cand_cnt, (unsigned)__popcll(m));     \
        base = __shfl(base, 0);                                                \
        if (p) {                                                               \
          unsigned off = base + (unsigned)__popcll(m & ((1ull << lane) - 1ull));\
          if (off < CAP) cand[off] = (kk);                                     \
        }                                                                      \
      }                                                                        \
    }
    CPCT(kx) CPCT(ky) CPCT(kz) CPCT(kw)
#undef CPCT
  }
  __syncthreads();
  const unsigned nc = cand_cnt;
  __syncthreads();

  if (nc >= K && nc <= CAP) {
    // ---- Phase R: exact 3-level radix select over LDS candidates ----
    clear_hist(hist, NBH); __syncthreads();
    for (unsigned i = tid; i < nc; i += TPB) atomicAdd(&hist[cand[i] >> 21], 1u);
    __syncthreads();
    find_top(hist, NBH, K, scan, &sel_bin, &sel_rem);
    const unsigned b1 = sel_bin, K2 = sel_rem;
    __syncthreads();

    clear_hist(hist, NBH); __syncthreads();
    for (unsigned i = tid; i < nc; i += TPB) {
      unsigned kk = cand[i];
      if ((kk >> 21) == b1) atomicAdd(&hist[(kk >> 10) & (NBH - 1)], 1u);
    }
    __syncthreads();
    find_top(hist, NBH, K2, scan, &sel_bin, &sel_rem);
    const unsigned b2 = sel_bin, K3 = sel_rem;
    __syncthreads();

    clear_hist(hist, NB3); __syncthreads();
    const unsigned pfx = (b1 << 11) | b2;
    for (unsigned i = tid; i < nc; i += TPB) {
      unsigned kk = cand[i];
      if ((kk >> 10) == pfx) atomicAdd(&hist[kk & (NB3 - 1)], 1u);
    }
    __syncthreads();
    find_top(hist, NB3, K3, scan, &sel_bin, &sel_rem);
    if (tid == 0) rowkey[row] = (b1 << 21) | (b2 << 10) | sel_bin;
  } else {
    // ---- Fallback: exact 3-pass global radix select (any data) ----
    clear_hist(hist, NBH); __syncthreads();
    for (int i = tid; i < n4; i += TPB) {
      f4 v = rowv[i];
      atomicAdd(&hist[f2key(v.x) >> 21], 1u);
      atomicAdd(&hist[f2key(v.y) >> 21], 1u);
      atomicAdd(&hist[f2key(v.z) >> 21], 1u);
      atomicAdd(&hist[f2key(v.w) >> 21], 1u);
    }
    __syncthreads();
    find_top(hist, NBH, K, scan, &sel_bin, &sel_rem);
    const unsigned b1 = sel_bin, K2 = sel_rem;
    __syncthreads();

    clear_hist(hist, NBH); __syncthreads();
    for (int i = tid; i < n4; i += TPB) {
      f4 v = rowv[i];
      unsigned kk;
      kk = f2key(v.x); if ((kk >> 21) == b1) atomicAdd(&hist[(kk >> 10) & (NBH - 1)], 1u);
      kk = f2key(v.y); if ((kk >> 21) == b1) atomicAdd(&hist[(kk >> 10) & (NBH - 1)], 1u);
      kk = f2key(v.z); if ((kk >> 21) == b1) atomicAdd(&hist[(kk >> 10) & (NBH - 1)], 1u);
      kk = f2key(v.w); if ((kk >> 21) == b1) atomicAdd(&hist[(kk >> 10) & (NBH - 1)], 1u);
    }
    __syncthreads();
    find_top(hist, NBH, K2, scan, &sel_bin, &sel_rem);
    const unsigned b2 = sel_bin, K3 = sel_rem;
    __syncthreads();

    clear_hist(hist, NB3); __syncthreads();
    const unsigned pfx = (b1 << 11) | b2;
    for (int i = tid; i < n4; i += TPB) {
      f4 v = rowv[i];
      unsigned kk;
      kk = f2key(v.x); if ((kk >> 10) == pfx) atomicAdd(&hist[kk & (NB3 - 1)], 1u);
      kk = f2key(v.y); if ((kk >> 10) == pfx) atomicAdd(&hist[kk & (NB3 - 1)], 1u);
      kk = f2key(v.z); if ((kk >> 10) == pfx) atomicAdd(&hist[kk & (NB3 - 1)], 1u);
      kk = f2key(v.w); if ((kk >> 10) == pfx) atomicAdd(&hist[kk & (NB3 - 1)], 1u);
    }
    __syncthreads();
    find_top(hist, NB3, K3, scan, &sel_bin, &sel_rem);
    if (tid == 0) rowkey[row] = (b1 << 21) | (b2 << 10) | sel_bin;
  }
}

__global__ void __launch_bounds__(TPB)
minreduce(const unsigned* __restrict__ rowkey, unsigned* __restrict__ thr, int n) {
  __shared__ unsigned s[TPB];
  unsigned m = 0xFFFFFFFFu;
  for (int i = threadIdx.x; i < n; i += TPB) m = min(m, rowkey[i]);
  s[threadIdx.x] = m;
  __syncthreads();
  for (int off = TPB / 2; off > 0; off >>= 1) {
    if (threadIdx.x < off) s[threadIdx.x] = min(s[threadIdx.x], s[threadIdx.x + off]);
    __syncthreads();
  }
  if (threadIdx.x == 0) thr[0] = s[0];
}

// Output stores are NONTEMPORAL: bypass LLC allocation so the input (exactly
// 256 MiB, LLC-resident after topk_select's read) stays cached for our reads.
__global__ void __launch_bounds__(TPB)
maskk(const f4* __restrict__ in, f4* __restrict__ out,
      const unsigned* __restrict__ thrkey, int n4) {
  const float thr = key2f(thrkey[0]);
  int idx = blockIdx.x * TPB + threadIdx.x;
  int stride = gridDim.x * TPB;
  for (int i = idx; i < n4; i += stride) {
    f4 v = in[i];
    f4 o;
    o.x = (v.x >= thr) ? v.x : 0.0f;
    o.y = (v.y >= thr) ? v.y : 0.0f;
    o.z = (v.z >= thr) ? v.z : 0.0f;
    o.w = (v.w >= thr) ? v.w : 0.0f;
    __builtin_nontemporal_store(o, &out[i]);
  }
}

extern "C" void kernel_launch(void* const* d_in, const int* in_sizes, int n_in,
                              void* d_out, int out_size, void* d_ws, size_t ws_size,
                              hipStream_t stream) {
  const float* in = (const float*)d_in[0];
  const int* kptr = (const int*)d_in[1];
  f4* out = (f4*)d_out;
  unsigned* rowkey = (unsigned*)d_ws;
  unsigned* thr = rowkey + 1024;

  const int B = in_sizes[0] / DCOLS;   // 1024 rows
  const int n4 = out_size / 4;         // 16M float4

  hipLaunchKernelGGL(topk_select, dim3(B), dim3(TPB), 0, stream, in, kptr, rowkey);
  hipLaunchKernelGGL(minreduce, dim3(1), dim3(TPB), 0, stream, rowkey, thr, B);
  hipLaunchKernelGGL(maskk, dim3(4096), dim3(TPB), 0, stream,
                     (const f4*)in, out, thr, n4);
}

// Round 6
// 482.948 us; speedup vs baseline: 1.1152x; 1.0073x over previous
//
#include <hip/hip_runtime.h>
#include <stdint.h>

#define TPB 256
#define NBH 2048    // histogram bins for bits [31:21] and [20:10]
#define NB3 1024    // bins for bits [9:0]
#define CAP 6144    // LDS candidate buffer (expected ~2600 for gaussian data)
#define DCOLS 65536
#define NSAMP 4096

typedef float f4 __attribute__((ext_vector_type(4)));

// Monotone transform: larger float -> larger unsigned key
__device__ __forceinline__ unsigned f2key(float f) {
  unsigned u = __float_as_uint(f);
  unsigned m = ((int)u >> 31) | 0x80000000u;
  return u ^ m;
}
__device__ __forceinline__ float key2f(unsigned k) {
  unsigned u = (k & 0x80000000u) ? (k ^ 0x80000000u) : ~k;
  return __uint_as_float(u);
}

__device__ __forceinline__ void clear_hist(unsigned* hist, int NB) {
  for (int i = threadIdx.x; i < NB; i += TPB) hist[i] = 0u;
}

// Find, scanning bins HIGH->LOW, the bin where cumulative count (from top)
// reaches K. All threads call; ends with a barrier. 3 barriers total.
__device__ void find_top(const unsigned* hist, int NB, unsigned K,
                         unsigned* scan, unsigned* selbin, unsigned* selrem) {
  const int tid = threadIdx.x;
  const int C = NB / TPB;
  unsigned cs = 0;
  for (int i = 0; i < C; ++i) cs += hist[tid * C + i];
  scan[tid] = cs;
  __syncthreads();
  if (tid < 64) {
    unsigned e0 = scan[tid * 4 + 0], e1 = scan[tid * 4 + 1];
    unsigned e2 = scan[tid * 4 + 2], e3 = scan[tid * 4 + 3];
    unsigned s = e0 + e1 + e2 + e3;
    unsigned suff = s;                       // wave suffix-scan (inclusive)
    for (int off = 1; off < 64; off <<= 1) {
      unsigned t = __shfl_down(suff, off);
      if (tid + off < 64) suff += t;
    }
    unsigned tail = suff - s;                // sum of chunks after my 4
    scan[tid * 4 + 3] = e3 + tail;
    scan[tid * 4 + 2] = e2 + e3 + tail;
    scan[tid * 4 + 1] = e1 + e2 + e3 + tail;
    scan[tid * 4 + 0] = s + tail;
  }
  __syncthreads();
  unsigned suff = scan[tid];                 // sum of chunks tid..TPB-1
  unsigned above = suff - cs;
  if (above < K && suff >= K) {              // exactly one thread wins
    unsigned cAbove = above;
    for (int bin = tid * C + C - 1; bin >= tid * C; --bin) {
      unsigned c = hist[bin];
      if (cAbove + c >= K) { *selbin = (unsigned)bin; *selrem = K - cAbove; break; }
      cAbove += c;
    }
  }
  __syncthreads();
}

__global__ void __launch_bounds__(TPB, 4)
topk_select(const float* __restrict__ in, const int* __restrict__ kptr,
            unsigned* __restrict__ thr) {
  __shared__ unsigned hist[NBH];
  __shared__ unsigned scan[TPB];
  __shared__ unsigned cand[CAP];
  __shared__ unsigned sel_bin, sel_rem, cand_cnt;

  const int tid = threadIdx.x;
  const int lane = tid & 63;
  const int row = blockIdx.x;
  const unsigned K = (unsigned)(*kptr);
  const f4* rowv = (const f4*)(in + (size_t)row * DCOLS);
  const int n4 = DCOLS / 4;

  // ---- Phase S: histogram a 4096-elem sample, pick pivot bin ----
  clear_hist(hist, NBH);
  if (tid == 0) cand_cnt = 0u;
  __syncthreads();
  {
    f4 s0 = rowv[tid], s1 = rowv[tid + TPB];
    f4 s2 = rowv[tid + 2 * TPB], s3 = rowv[tid + 3 * TPB];
#define HSAMP(v)                                                               \
    atomicAdd(&hist[f2key(v.x) >> 21], 1u);                                    \
    atomicAdd(&hist[f2key(v.y) >> 21], 1u);                                    \
    atomicAdd(&hist[f2key(v.z) >> 21], 1u);                                    \
    atomicAdd(&hist[f2key(v.w) >> 21], 1u);
    HSAMP(s0) HSAMP(s1) HSAMP(s2) HSAMP(s3)
#undef HSAMP
  }
  __syncthreads();
  unsigned ksamp = K >> 3;                 // 2x oversample vs K*NSAMP/DCOLS
  if (ksamp < 32u) ksamp = 32u;
  if (ksamp > NSAMP - 1) ksamp = NSAMP - 1;
  find_top(hist, NBH, ksamp, scan, &sel_bin, &sel_rem);
  const unsigned tlo = sel_bin << 21;      // pivot: bin floor <= ksamp-th sample
  __syncthreads();

  // ---- Phase C: full-row read (4 loads in flight), wave-aggregated
  //      compaction of keys >= tlo, with wave early-out ----
#define CPCT(kk)                                                               \
    {                                                                          \
      bool p = (kk) >= tlo;                                                    \
      unsigned long long m = __ballot(p);                                      \
      if (m) {                                                                 \
        unsigned base = 0;                                                     \
        if (lane == 0) base = atomicAdd(&cand_cnt, (unsigned)__popcll(m));     \
        base = __shfl(base, 0);                                                \
        if (p) {                                                               \
          unsigned off = base + (unsigned)__popcll(m & ((1ull << lane) - 1ull));\
          if (off < CAP) cand[off] = (kk);                                     \
        }                                                                      \
      }                                                                        \
    }
#define PROC(v)                                                                \
    {                                                                          \
      unsigned kx = f2key(v.x), ky = f2key(v.y);                               \
      unsigned kz = f2key(v.z), kw = f2key(v.w);                               \
      bool any = (kx >= tlo) | (ky >= tlo) | (kz >= tlo) | (kw >= tlo);        \
      if (__ballot(any)) { CPCT(kx) CPCT(ky) CPCT(kz) CPCT(kw) }               \
    }
  for (int base = 0; base < n4; base += TPB * 4) {
    f4 v0 = rowv[base + tid];
    f4 v1 = rowv[base + tid + TPB];
    f4 v2 = rowv[base + tid + 2 * TPB];
    f4 v3 = rowv[base + tid + 3 * TPB];
    PROC(v0) PROC(v1) PROC(v2) PROC(v3)
  }
#undef PROC
  __syncthreads();
  const unsigned nc = cand_cnt;
  __syncthreads();

  unsigned rk;  // this row's kth-largest as monotone key
  if (nc >= K && nc <= CAP) {
    // ---- Phase R: exact 3-level radix select over LDS candidates ----
    clear_hist(hist, NBH); __syncthreads();
    for (unsigned i = tid; i < nc; i += TPB) atomicAdd(&hist[cand[i] >> 21], 1u);
    __syncthreads();
    find_top(hist, NBH, K, scan, &sel_bin, &sel_rem);
    const unsigned b1 = sel_bin, K2 = sel_rem;
    __syncthreads();

    clear_hist(hist, NBH); __syncthreads();
    for (unsigned i = tid; i < nc; i += TPB) {
      unsigned kk = cand[i];
      if ((kk >> 21) == b1) atomicAdd(&hist[(kk >> 10) & (NBH - 1)], 1u);
    }
    __syncthreads();
    find_top(hist, NBH, K2, scan, &sel_bin, &sel_rem);
    const unsigned b2 = sel_bin, K3 = sel_rem;
    __syncthreads();

    clear_hist(hist, NB3); __syncthreads();
    const unsigned pfx = (b1 << 11) | b2;
    for (unsigned i = tid; i < nc; i += TPB) {
      unsigned kk = cand[i];
      if ((kk >> 10) == pfx) atomicAdd(&hist[kk & (NB3 - 1)], 1u);
    }
    __syncthreads();
    find_top(hist, NB3, K3, scan, &sel_bin, &sel_rem);
    rk = (b1 << 21) | (b2 << 10) | sel_bin;
  } else {
    // ---- Fallback: exact 3-pass global radix select (any data) ----
    clear_hist(hist, NBH); __syncthreads();
    for (int i = tid; i < n4; i += TPB) {
      f4 v = rowv[i];
      atomicAdd(&hist[f2key(v.x) >> 21], 1u);
      atomicAdd(&hist[f2key(v.y) >> 21], 1u);
      atomicAdd(&hist[f2key(v.z) >> 21], 1u);
      atomicAdd(&hist[f2key(v.w) >> 21], 1u);
    }
    __syncthreads();
    find_top(hist, NBH, K, scan, &sel_bin, &sel_rem);
    const unsigned b1 = sel_bin, K2 = sel_rem;
    __syncthreads();

    clear_hist(hist, NBH); __syncthreads();
    for (int i = tid; i < n4; i += TPB) {
      f4 v = rowv[i];
      unsigned kk;
      kk = f2key(v.x); if ((kk >> 21) == b1) atomicAdd(&hist[(kk >> 10) & (NBH - 1)], 1u);
      kk = f2key(v.y); if ((kk >> 21) == b1) atomicAdd(&hist[(kk >> 10) & (NBH - 1)], 1u);
      kk = f2key(v.z); if ((kk >> 21) == b1) atomicAdd(&hist[(kk >> 10) & (NBH - 1)], 1u);
      kk = f2key(v.w); if ((kk >> 21) == b1) atomicAdd(&hist[(kk >> 10) & (NBH - 1)], 1u);
    }
    __syncthreads();
    find_top(hist, NBH, K2, scan, &sel_bin, &sel_rem);
    const unsigned b2 = sel_bin, K3 = sel_rem;
    __syncthreads();

    clear_hist(hist, NB3); __syncthreads();
    const unsigned pfx = (b1 << 11) | b2;
    for (int i = tid; i < n4; i += TPB) {
      f4 v = rowv[i];
      unsigned kk;
      kk = f2key(v.x); if ((kk >> 10) == pfx) atomicAdd(&hist[kk & (NB3 - 1)], 1u);
      kk = f2key(v.y); if ((kk >> 10) == pfx) atomicAdd(&hist[kk & (NB3 - 1)], 1u);
      kk = f2key(v.z); if ((kk >> 10) == pfx) atomicAdd(&hist[kk & (NB3 - 1)], 1u);
      kk = f2key(v.w); if ((kk >> 10) == pfx) atomicAdd(&hist[kk & (NB3 - 1)], 1u);
    }
    __syncthreads();
    find_top(hist, NB3, K3, scan, &sel_bin, &sel_rem);
    rk = (b1 << 21) | (b2 << 10) | sel_bin;
  }
#undef CPCT
  // Global threshold = min over rows; device-scope atomicMin on monotone key.
  if (tid == 0) atomicMin(thr, rk);
}

// Output stores are NONTEMPORAL: bypass LLC allocation so the input (exactly
// 256 MiB, LLC-resident after topk_select's read) stays cached for our reads.
__global__ void __launch_bounds__(TPB)
maskk(const f4* __restrict__ in, f4* __restrict__ out,
      const unsigned* __restrict__ thrkey, int n4) {
  const float thr = key2f(thrkey[0]);
  int idx = blockIdx.x * TPB + threadIdx.x;
  int stride = gridDim.x * TPB;
  for (int i = idx; i < n4; i += stride) {
    f4 v = in[i];
    f4 o;
    o.x = (v.x >= thr) ? v.x : 0.0f;
    o.y = (v.y >= thr) ? v.y : 0.0f;
    o.z = (v.z >= thr) ? v.z : 0.0f;
    o.w = (v.w >= thr) ? v.w : 0.0f;
    __builtin_nontemporal_store(o, &out[i]);
  }
}

extern "C" void kernel_launch(void* const* d_in, const int* in_sizes, int n_in,
                              void* d_out, int out_size, void* d_ws, size_t ws_size,
                              hipStream_t stream) {
  const float* in = (const float*)d_in[0];
  const int* kptr = (const int*)d_in[1];
  f4* out = (f4*)d_out;
  unsigned* thr = (unsigned*)d_ws;

  const int B = in_sizes[0] / DCOLS;   // 1024 rows
  const int n4 = out_size / 4;         // 16M float4

  hipMemsetAsync(thr, 0xFF, 4, stream);   // thr = 0xFFFFFFFF (max key)
  hipLaunchKernelGGL(topk_select, dim3(B), dim3(TPB), 0, stream, in, kptr, thr);
  hipLaunchKernelGGL(maskk, dim3(4096), dim3(TPB), 0, stream,
                     (const f4*)in, out, thr, n4);
}